// Round 20
// baseline (3768.133 us; speedup 1.0000x reference)
//
#include <hip/hip_runtime.h>
#include <cstdint>
#include <cstddef>

#define Dm 768
#define Hh 12
#define DHd 64
#define Ll 12
#define Vv 50257
#define Vp 50304          // padded vocab (393*128)
#define Tt 4096
#define Ff 3072
#define QS 2304           // fused qkv row stride
#define ETA (1.0f/16.0f)

typedef __attribute__((ext_vector_type(8))) _Float16 half8;
typedef __attribute__((ext_vector_type(8))) unsigned short ushort8;
typedef __attribute__((ext_vector_type(4))) float f32x4;

static __device__ __forceinline__ unsigned short f2h(float f){
  union { _Float16 h; unsigned short u; } c; c.h = (_Float16)f; return c.u;
}
static __device__ __forceinline__ float h2f(unsigned short u){
  union { unsigned short u; _Float16 h; } c; c.u = u; return (float)c.h;
}
static __device__ __forceinline__ float4 h4(ushort4 u){
  float4 f; f.x=h2f(u.x); f.y=h2f(u.y); f.z=h2f(u.z); f.w=h2f(u.w); return f;
}
// async global->LDS, 16B per lane; dest = wave-uniform base + lane*16
static __device__ __forceinline__ void gload16(const void* g, void* l){
  __builtin_amdgcn_global_load_lds((const __attribute__((address_space(1))) unsigned int*)g,
                                   (__attribute__((address_space(3))) unsigned int*)l, 16, 0, 0);
}
// panel byte offset for element (row, k) of plane with M rows
static __device__ __forceinline__ size_t pan_off(int ks, size_t M, int row, int k){
  return ((size_t)ks*M + row)*128 + (size_t)(((k*2) ^ ((row & 7) << 4)));
}

// ---- weight transform: f32 [L][K][Ns] -> swizzle-baked f16 panels [L][K/64][Nd][64] (+coff) ----
__global__ __launch_bounds__(256)
void convwt_kernel(const float* __restrict__ src, unsigned short* __restrict__ dst,
                   int K, int Ns, int Nd, int coff)
{
  const int l  = blockIdx.y;
  const int nb = blockIdx.x % (Ns/64);
  const int ks = blockIdx.x / (Ns/64);
  const int t  = threadIdx.x;
  __shared__ float tile[64][65];
  const float* W = src + (size_t)l*K*Ns;
  {
    const int r = t >> 2, c0 = (t & 3) * 16;
    const float* s = W + (size_t)(ks*64 + r)*Ns + nb*64 + c0;
    #pragma unroll
    for (int i = 0; i < 4; ++i) {
      const float4 f = *(const float4*)(s + i*4);
      tile[r][c0+i*4+0]=f.x; tile[r][c0+i*4+1]=f.y; tile[r][c0+i*4+2]=f.z; tile[r][c0+i*4+3]=f.w;
    }
  }
  __syncthreads();
  const int n   = t >> 2;
  const int kk0 = (t & 3) * 16;
  const int gn  = coff + nb*64 + n;
  unsigned short bh[16];
  #pragma unroll
  for (int i = 0; i < 16; ++i) bh[i] = f2h(tile[kk0 + i][n]);
  const size_t rowb = ((size_t)l*K*Nd + ((size_t)ks*Nd + gn)*64) * 2;
  const int swz = (gn & 7) << 4;
  char* bD = (char*)dst + rowb;
  *(ushort8*)(bD + ((kk0*2)      ^ swz)) = *(ushort8*)&bh[0];
  *(ushort8*)(bD + ((kk0*2 + 16) ^ swz)) = *(ushort8*)&bh[8];
}

// ---- tok f32 -> swizzle-baked f16 panels [12][Vp][64] ----
__global__ __launch_bounds__(256)
void convtok_kernel(const float* __restrict__ src, unsigned short* __restrict__ dst)
{
  const int total = 12 * Vp * 8;
  for (int gi = blockIdx.x*256 + threadIdx.x; gi < total; gi += gridDim.x*256) {
    const int j  = gi & 7;
    const int v  = (gi >> 3) % Vp;
    const int ks = gi / (8 * Vp);
    ushort8 u;
    if (v < Vv) {
      const float* s = src + (size_t)v*Dm + ks*64 + j*8;
      const float4 f0 = *(const float4*)s, f1 = *(const float4*)(s+4);
      u[0]=f2h(f0.x); u[1]=f2h(f0.y); u[2]=f2h(f0.z); u[3]=f2h(f0.w);
      u[4]=f2h(f1.x); u[5]=f2h(f1.y); u[6]=f2h(f1.z); u[7]=f2h(f1.w);
    } else {
      #pragma unroll
      for (int q = 0; q < 8; ++q) u[q] = 0;
    }
    const size_t rowb = ((size_t)ks*Vp + v) * 128;
    *(ushort8*)((char*)dst + rowb + ((j*16) ^ ((v&7)<<4))) = u;
  }
}

// ---- RoPE cos/sin table ----
__global__ __launch_bounds__(256)
void rtab_kernel(float* __restrict__ rt)
{
  const int idx = blockIdx.x*256 + threadIdx.x;
  if (idx >= 1024*64) return;
  const int s = idx >> 6, c = idx & 63, d = c & 31;
  const float freq = powf(10000.0f, -(float)d * (1.0f/32.0f));
  const float ang  = (float)s * freq;
  rt[idx] = (c < 32) ? cosf(ang) : sinf(ang);
}

// ---------------- LayerNorm; OMODE: 0=f32 rows, 1=f16 panels ----------------
template<int OMODE>
__global__ __launch_bounds__(256)
void ln_kernel(const float* __restrict__ in, const int* __restrict__ ids,
               const float* __restrict__ w, const float* __restrict__ b,
               void* __restrict__ o1)
{
  const int row = blockIdx.x;
  const int t = threadIdx.x;
  const float* px = in + (ids ? (size_t)ids[row] * Dm : (size_t)row * Dm);
  float x0 = px[t], x1 = px[t+256], x2 = px[t+512];
  float s  = x0 + x1 + x2;
  float s2 = x0*x0 + x1*x1 + x2*x2;
  #pragma unroll
  for (int o = 32; o > 0; o >>= 1) { s += __shfl_xor(s, o); s2 += __shfl_xor(s2, o); }
  __shared__ float ls[4], ls2[4];
  if ((t & 63) == 0) { ls[t>>6] = s; ls2[t>>6] = s2; }
  __syncthreads();
  s  = ls[0]+ls[1]+ls[2]+ls[3];
  s2 = ls2[0]+ls2[1]+ls2[2]+ls2[3];
  const float mu  = s * (1.0f/Dm);
  const float var = s2 * (1.0f/Dm) - mu*mu;
  const float rs  = rsqrtf(var + 1e-5f);
  #pragma unroll
  for (int i = 0; i < 3; ++i) {
    const int c = t + i*256;
    const float xv = (i==0) ? x0 : (i==1) ? x1 : x2;
    const float vv_ = (xv-mu)*rs*w[c] + b[c];
    if (OMODE == 0) {
      ((float*)o1)[(size_t)row * Dm + c] = vv_;
    } else {
      *(unsigned short*)((char*)o1 + pan_off(c >> 6, Tt, row, c & 63)) = f2h(vv_);
    }
  }
}

// ---------------- TTT scan, fused RoPE, dbuf k/q LDS, 2 barriers/chunk, v prefetched ----------------
static __device__ __forceinline__ float4 rot4(float4 a, float4 p, float4 rc, float4 rs, bool hi){
  float4 o;
  if (hi) { o.x = p.x*rs.x + a.x*rc.x; o.y = p.y*rs.y + a.y*rc.y;
            o.z = p.z*rs.z + a.z*rc.z; o.w = p.w*rs.w + a.w*rc.w; }
  else    { o.x = a.x*rc.x - p.x*rs.x; o.y = a.y*rc.y - p.y*rs.y;
            o.z = a.z*rc.z - p.z*rs.z; o.w = a.w*rc.w - p.w*rs.w; }
  return o;
}

__global__ __launch_bounds__(256)
void ttt_scan_kernel(const unsigned short* __restrict__ qkv, const float* __restrict__ rt,
                     unsigned short* __restrict__ ob)
{
  const int head = blockIdx.x >> 2;
  const int es   = blockIdx.x & 3;
  const int b  = head / Hh;
  const int hd = head % Hh;
  const int t  = threadIdx.x;
  __shared__ float Wm[16][68];
  __shared__ float kms[2][16][68];
  __shared__ float qms[2][16][68];
  __shared__ float EsT[16][20];
  __shared__ float Asc[16][20];

  const int e   = t & 15;
  const int m16 = t >> 4;
  const int sr  = t >> 4;
  const int sc  = (t & 15) * 4;
  const bool hi = (sc >= 32);

  for (int i = t; i < 16*68; i += 256) ((float*)Wm)[i] = 0.0f;

  const int tb0 = b * 1024;
  const size_t gbase = (size_t)hd * DHd;

  {
    const size_t ro = (size_t)(tb0 + sr)*QS + gbase;
    const float4 kr = h4(*(const ushort4*)&qkv[ro + Dm + sc]);
    const float4 kp = h4(*(const ushort4*)&qkv[ro + Dm + (sc^32)]);
    const float4 qr = h4(*(const ushort4*)&qkv[ro + sc]);
    const float4 qp = h4(*(const ushort4*)&qkv[ro + (sc^32)]);
    const float4 rc = *(const float4*)&rt[sr*64 + (sc&31)];
    const float4 rs = *(const float4*)&rt[sr*64 + 32 + (sc&31)];
    *(float4*)&kms[0][sr][sc] = rot4(kr, kp, rc, rs, hi);
    *(float4*)&qms[0][sr][sc] = rot4(qr, qp, rc, rs, hi);
  }
  float4 krR, qrR;
  {
    const size_t ro = (size_t)(tb0 + 16 + sr)*QS + gbase;
    const float4 kr = h4(*(const ushort4*)&qkv[ro + Dm + sc]);
    const float4 kp = h4(*(const ushort4*)&qkv[ro + Dm + (sc^32)]);
    const float4 qr = h4(*(const ushort4*)&qkv[ro + sc]);
    const float4 qp = h4(*(const ushort4*)&qkv[ro + (sc^32)]);
    const float4 rc = *(const float4*)&rt[(16+sr)*64 + (sc&31)];
    const float4 rs = *(const float4*)&rt[(16+sr)*64 + 32 + (sc&31)];
    krR = rot4(kr, kp, rc, rs, hi);
    qrR = rot4(qr, qp, rc, rs, hi);
  }
  float vreg = h2f(qkv[(size_t)(tb0 + m16)*QS + 2*Dm + gbase + es*16 + e]);
  __syncthreads();

  for (int c = 0; c < 64; ++c) {
    const int buf = c & 1;
    const int tb = tb0 + c*16;
    float aE = -vreg, aO = 0.0f, aA = 0.0f;
    #pragma unroll
    for (int d4 = 0; d4 < 64; d4 += 4) {
      const float4 wv = *(const float4*)&Wm[e][d4];
      const float4 km = *(const float4*)&kms[buf][m16][d4];
      const float4 qm = *(const float4*)&qms[buf][m16][d4];
      const float4 ke = *(const float4*)&kms[buf][e][d4];
      aE += km.x*wv.x + km.y*wv.y + km.z*wv.z + km.w*wv.w;
      aO += qm.x*wv.x + qm.y*wv.y + qm.z*wv.z + qm.w*wv.w;
      aA += qm.x*ke.x + qm.y*ke.y + qm.z*ke.z + qm.w*ke.w;
    }
    EsT[e][m16] = aE;
    Asc[m16][e] = (e <= m16) ? (-ETA * aA) : 0.0f;
    if (c < 63) vreg = h2f(qkv[(size_t)(tb + 16 + m16)*QS + 2*Dm + gbase + es*16 + e]);
    __syncthreads();
    float esr[16];
    float acc = aO;
    #pragma unroll
    for (int n4 = 0; n4 < 16; n4 += 4) {
      const float4 ev = *(const float4*)&EsT[e][n4];
      const float4 av = *(const float4*)&Asc[m16][n4];
      esr[n4]=ev.x; esr[n4+1]=ev.y; esr[n4+2]=ev.z; esr[n4+3]=ev.w;
      acc += av.x*ev.x + av.y*ev.y + av.z*ev.z + av.w*ev.w;
    }
    *(unsigned short*)((char*)ob + pan_off(hd, Tt, tb + m16, es*16 + e)) = f2h(acc);
    {
      const int d0 = m16 * 4;
      float4 wacc; wacc.x = 0.0f; wacc.y = 0.0f; wacc.z = 0.0f; wacc.w = 0.0f;
      #pragma unroll
      for (int m = 0; m < 16; ++m) {
        const float4 km = *(const float4*)&kms[buf][m][d0];
        const float ev = esr[m];
        wacc.x += km.x*ev; wacc.y += km.y*ev; wacc.z += km.z*ev; wacc.w += km.w*ev;
      }
      float4 wv = *(float4*)&Wm[e][d0];
      wv.x -= ETA*wacc.x; wv.y -= ETA*wacc.y; wv.z -= ETA*wacc.z; wv.w -= ETA*wacc.w;
      *(float4*)&Wm[e][d0] = wv;
    }
    if (c < 63) {
      *(float4*)&kms[buf^1][sr][sc] = krR;
      *(float4*)&qms[buf^1][sr][sc] = qrR;
    }
    if (c < 62) {
      const size_t ro = (size_t)(tb + 32 + sr)*QS + gbase;
      const float4 kr = h4(*(const ushort4*)&qkv[ro + Dm + sc]);
      const float4 kp = h4(*(const ushort4*)&qkv[ro + Dm + (sc^32)]);
      const float4 qr = h4(*(const ushort4*)&qkv[ro + sc]);
      const float4 qp = h4(*(const ushort4*)&qkv[ro + (sc^32)]);
      const int sN = (c+2)*16 + sr;
      const float4 rc = *(const float4*)&rt[sN*64 + (sc&31)];
      const float4 rs = *(const float4*)&rt[sN*64 + 32 + (sc&31)];
      krR = rot4(kr, kp, rc, rs, hi);
      qrR = rot4(qr, qp, rc, rs, hi);
    }
    __syncthreads();
  }
}

static __device__ __forceinline__ float gelu_f(float x){
  const float u = 0.7978845608028654f * (x + 0.044715f * x*x*x);
  return 0.5f * x * (1.0f + tanhf(u));
}

// ---------------- f16 MFMA GEMM (256-thr, single-buffer, gload_lds panels, KP k-panels/stage) ----------------
// OUT: 0=f32 rows (+RES), 1=f16 panel plane, 2=f16 rows
template<int TM, int TN, int KP, bool BIAS, bool GELU_, bool RES, int OUT>
__global__ __launch_bounds__(256)
void gemm_kernel(const unsigned short* __restrict__ A, const unsigned short* __restrict__ B,
                 const float* __restrict__ bias, const float* __restrict__ res,
                 void* __restrict__ o1, int M, int N, int K)
{
  constexpr int FM = TM / 32;
  constexpr int FN = TN / 32;
  __shared__ __attribute__((aligned(16))) unsigned short As[KP*TM*64];
  __shared__ __attribute__((aligned(16))) unsigned short Bs[KP*TN*64];
  const int t    = threadIdx.x;
  const int lane = t & 63;
  const int fr   = lane & 15;
  const int fg   = lane >> 4;
  const int wave = t >> 6;
  const int wm   = (wave >> 1) * (TM/2);
  const int wn   = (wave & 1) * (TN/2);
  const int row0 = blockIdx.y * TM;
  const int n0   = blockIdx.x * TN;

  f32x4 acc[FM][FN];
  #pragma unroll
  for (int i = 0; i < FM; ++i)
    #pragma unroll
    for (int j = 0; j < FN; ++j)
      #pragma unroll
      for (int r = 0; r < 4; ++r) acc[i][j][r] = 0.0f;

  const int NI = K / (64*KP);
  for (int it = 0; it < NI; ++it) {
    #pragma unroll
    for (int p = 0; p < KP; ++p) {
      const int ks = it*KP + p;
      {
        const char* gB = (const char*)B + ((size_t)ks*N + n0) * 128;
        char* lB = (char*)Bs + p*(TN*128);
        #pragma unroll
        for (int r = 0; r < TN/32; ++r) {
          const int chunk = (r*4 + wave) * 1024;
          gload16(gB + chunk + lane*16, lB + chunk);
        }
      }
      {
        const char* gA = (const char*)A + ((size_t)ks*M + row0) * 128;
        char* lA = (char*)As + p*(TM*128);
        #pragma unroll
        for (int r = 0; r < TM/32; ++r) {
          const int chunk = (r*4 + wave) * 1024;
          gload16(gA + chunk + lane*16, lA + chunk);
        }
      }
    }
    __syncthreads();
    #pragma unroll
    for (int p = 0; p < KP; ++p) {
      #pragma unroll
      for (int kh = 0; kh < 2; ++kh) {
        half8 af[FM], bf[FN];
        const int swz = (fr & 7) << 4;
        #pragma unroll
        for (int mt = 0; mt < FM; ++mt)
          af[mt] = *(const half8*)((const char*)As + p*(TM*128) + (((wm + mt*16 + fr)*128 + kh*64 + fg*16) ^ swz));
        #pragma unroll
        for (int nt = 0; nt < FN; ++nt)
          bf[nt] = *(const half8*)((const char*)Bs + p*(TN*128) + (((wn + nt*16 + fr)*128 + kh*64 + fg*16) ^ swz));
        #pragma unroll
        for (int mt = 0; mt < FM; ++mt)
          #pragma unroll
          for (int nt = 0; nt < FN; ++nt)
            acc[mt][nt] = __builtin_amdgcn_mfma_f32_16x16x32_f16(af[mt], bf[nt], acc[mt][nt], 0, 0, 0);
      }
    }
    __syncthreads();
  }

  #pragma unroll
  for (int mt = 0; mt < FM; ++mt) {
    #pragma unroll
    for (int nt = 0; nt < FN; ++nt) {
      const int col = n0 + wn + nt*16 + fr;
      const int rbase = row0 + wm + mt*16 + fg*4;
      const float bcol = BIAS ? bias[col] : 0.0f;
      #pragma unroll
      for (int r = 0; r < 4; ++r) {
        float val = acc[mt][nt][r];
        if (BIAS)  val += bcol;
        if (GELU_) val = gelu_f(val);
        if (OUT == 1) {
          *(unsigned short*)((char*)o1 + pan_off(col >> 6, M, rbase + r, col & 63)) = f2h(val);
        } else if (OUT == 2) {
          ((unsigned short*)o1)[(size_t)(rbase + r) * N + col] = f2h(val);
        } else {
          const size_t off = (size_t)(rbase + r) * N + col;
          float v2 = val;
          if (RES) v2 += res[off];
          ((float*)o1)[off] = v2;
        }
      }
    }
  }
}

// ---------------- big-tile f16 GEMM: 256x128, 512 thr (8 waves 4m x 2n), panels both sides ----------------
// OUT: 1=f16 panel plane, 2=f16 rows
template<bool BIAS, bool GELU_, int OUT>
__global__ __launch_bounds__(512)
void gemm_big(const unsigned short* __restrict__ A, const unsigned short* __restrict__ B,
              const float* __restrict__ bias, void* __restrict__ o1, int M, int N, int K)
{
  __shared__ __attribute__((aligned(16))) unsigned short As[256*64];  // 32 KB
  __shared__ __attribute__((aligned(16))) unsigned short Bs[128*64];  // 16 KB
  const int t    = threadIdx.x;
  const int lane = t & 63;
  const int fr   = lane & 15;
  const int fg   = lane >> 4;
  const int w    = t >> 6;                   // 0..7
  const int wm   = (w >> 1) * 64;            // 4 m-waves
  const int wn   = (w & 1) * 64;             // 2 n-waves
  const int row0 = blockIdx.y * 256;
  const int n0   = blockIdx.x * 128;

  f32x4 acc[4][4];
  #pragma unroll
  for (int i = 0; i < 4; ++i)
    #pragma unroll
    for (int j = 0; j < 4; ++j)
      #pragma unroll
      for (int r = 0; r < 4; ++r) acc[i][j][r] = 0.0f;

  const int NK = K >> 6;
  for (int ks = 0; ks < NK; ++ks) {
    { // A: 32 KB (32 chunks; 8 waves x 4)
      const char* gA = (const char*)A + ((size_t)ks*M + row0) * 128;
      #pragma unroll
      for (int r = 0; r < 4; ++r) {
        const int chunk = (r*8 + w) * 1024;
        gload16(gA + chunk + lane*16, (char*)As + chunk);
      }
    }
    { // B: 16 KB (16 chunks; 8 waves x 2)
      const char* gB = (const char*)B + ((size_t)ks*N + n0) * 128;
      #pragma unroll
      for (int r = 0; r < 2; ++r) {
        const int chunk = (r*8 + w) * 1024;
        gload16(gB + chunk + lane*16, (char*)Bs + chunk);
      }
    }
    __syncthreads();
    #pragma unroll
    for (int kh = 0; kh < 2; ++kh) {
      half8 af[4], bf[4];
      const int swz = (fr & 7) << 4;
      #pragma unroll
      for (int mt = 0; mt < 4; ++mt)
        af[mt] = *(const half8*)((const char*)As + (((wm + mt*16 + fr)*128 + kh*64 + fg*16) ^ swz));
      #pragma unroll
      for (int nt = 0; nt < 4; ++nt)
        bf[nt] = *(const half8*)((const char*)Bs + (((wn + nt*16 + fr)*128 + kh*64 + fg*16) ^ swz));
      #pragma unroll
      for (int mt = 0; mt < 4; ++mt)
        #pragma unroll
        for (int nt = 0; nt < 4; ++nt)
          acc[mt][nt] = __builtin_amdgcn_mfma_f32_16x16x32_f16(af[mt], bf[nt], acc[mt][nt], 0, 0, 0);
    }
    __syncthreads();
  }

  #pragma unroll
  for (int mt = 0; mt < 4; ++mt) {
    #pragma unroll
    for (int nt = 0; nt < 4; ++nt) {
      const int col = n0 + wn + nt*16 + fr;
      const int rbase = row0 + wm + mt*16 + fg*4;
      const float bcol = BIAS ? bias[col] : 0.0f;
      #pragma unroll
      for (int r = 0; r < 4; ++r) {
        float val = acc[mt][nt][r];
        if (BIAS)  val += bcol;
        if (GELU_) val = gelu_f(val);
        if (OUT == 1) {
          *(unsigned short*)((char*)o1 + pan_off(col >> 6, M, rbase + r, col & 63)) = f2h(val);
        } else {
          ((unsigned short*)o1)[(size_t)(rbase + r) * N + col] = f2h(val);
        }
      }
    }
  }
}

// ---------------- logits GEMM: 256x128 block tile, 512 thr ----------------
template<bool PRE>
__global__ __launch_bounds__(512)
void logits_kernel(const unsigned short* __restrict__ hop, const float* __restrict__ tok,
                   const unsigned short* __restrict__ tokb, float* __restrict__ C)
{
  __shared__ __attribute__((aligned(16))) unsigned short As[256*64];
  __shared__ __attribute__((aligned(16))) unsigned short Bs[128*64];
  int bid = blockIdx.x;
  bid = (bid & 7) * 786 + (bid >> 3);
  const int n0   = (bid >> 4) * 128;
  const int row0 = (bid & 15) * 256;

  const int t    = threadIdx.x;
  const int lane = t & 63;
  const int fr   = lane & 15;
  const int fg   = lane >> 4;
  const int w    = t >> 6;
  const int wm   = (w >> 1) * 64;
  const int wn   = (w & 1) * 64;
  const int arow = t >> 2;
  const int ach  = (t & 3) * 16;

  f32x4 acc[4][4];
  #pragma unroll
  for (int i = 0; i < 4; ++i)
    #pragma unroll
    for (int j = 0; j < 4; ++j)
      #pragma unroll
      for (int r = 0; r < 4; ++r) acc[i][j][r] = 0.0f;

  for (int ks = 0; ks < 12; ++ks) {
    {
      const char* gA = (const char*)hop + ((size_t)ks*Tt + row0) * 128;
      #pragma unroll
      for (int r = 0; r < 4; ++r) {
        const int chunk = (r*8 + w) * 1024;
        gload16(gA + chunk + lane*16, (char*)As + chunk);
      }
    }
    if (PRE) {
      const char* gB = (const char*)tokb + ((size_t)ks*Vp + n0) * 128;
      #pragma unroll
      for (int r = 0; r < 2; ++r) {
        const int chunk = (r*8 + w) * 1024;
        gload16(gB + chunk + lane*16, (char*)Bs + chunk);
      }
    } else {
      const int brow = n0 + arow;
      ushort8 u;
      if (brow < Vv) {
        const float* src = &tok[(size_t)brow * Dm + ks*64 + ach];
        const float4 f0 = *(const float4*)src;
        const float4 f1 = *(const float4*)(src + 4);
        const float4 f2 = *(const float4*)(src + 8);
        const float4 f3 = *(const float4*)(src + 12);
        u[0]=f2h(f0.x); u[1]=f2h(f0.y); u[2]=f2h(f0.z); u[3]=f2h(f0.w);
        u[4]=f2h(f1.x); u[5]=f2h(f1.y); u[6]=f2h(f1.z); u[7]=f2h(f1.w);
        const int byt0 = (arow*128 + ach*2) ^ ((arow & 7) << 4);
        *(ushort8*)((char*)Bs + byt0) = u;
        u[0]=f2h(f2.x); u[1]=f2h(f2.y); u[2]=f2h(f2.z); u[3]=f2h(f2.w);
        u[4]=f2h(f3.x); u[5]=f2h(f3.y); u[6]=f2h(f3.z); u[7]=f2h(f3.w);
        const int byt1 = (arow*128 + ach*2 + 16) ^ ((arow & 7) << 4);
        *(ushort8*)((char*)Bs + byt1) = u;
      } else {
        #pragma unroll
        for (int q = 0; q < 8; ++q) u[q] = 0;
        const int byt0 = (arow*128 + ach*2) ^ ((arow & 7) << 4);
        const int byt1 = (arow*128 + ach*2 + 16) ^ ((arow & 7) << 4);
        *(ushort8*)((char*)Bs + byt0) = u;
        *(ushort8*)((char*)Bs + byt1) = u;
      }
    }
    __syncthreads();
    #pragma unroll
    for (int kh = 0; kh < 2; ++kh) {
      half8 af[4], bf[4];
      const int swz = (fr & 7) << 4;
      #pragma unroll
      for (int mt = 0; mt < 4; ++mt)
        af[mt] = *(const half8*)((const char*)As + (((wm + mt*16 + fr)*128 + kh*64 + fg*16) ^ swz));
      #pragma unroll
      for (int nt = 0; nt < 4; ++nt)
        bf[nt] = *(const half8*)((const char*)Bs + (((wn + nt*16 + fr)*128 + kh*64 + fg*16) ^ swz));
      #pragma unroll
      for (int mt = 0; mt < 4; ++mt)
        #pragma unroll
        for (int nt = 0; nt < 4; ++nt)
          acc[mt][nt] = __builtin_amdgcn_mfma_f32_16x16x32_f16(af[mt], bf[nt], acc[mt][nt], 0, 0, 0);
    }
    __syncthreads();
  }

  #pragma unroll
  for (int mt = 0; mt < 4; ++mt) {
    #pragma unroll
    for (int nt = 0; nt < 4; ++nt) {
      const int col = n0 + wn + nt*16 + fr;
      if (col < Vv) {
        const int rbase = row0 + wm + mt*16 + fg*4;
        #pragma unroll
        for (int r = 0; r < 4; ++r)
          C[(size_t)(rbase + r) * Vv + col] = acc[mt][nt][r];
      }
    }
  }
}

// ---------------- host-side orchestration ----------------
extern "C" void kernel_launch(void* const* d_in, const int* in_sizes, int n_in,
                              void* d_out, int out_size, void* d_ws, size_t ws_size,
                              hipStream_t stream)
{
  const int*   ids = (const int*)  d_in[0];
  const float* tok = (const float*)d_in[1];
  const float* ew  = (const float*)d_in[2];
  const float* eb  = (const float*)d_in[3];
  const float* wq  = (const float*)d_in[4];
  const float* wk  = (const float*)d_in[5];
  const float* wv  = (const float*)d_in[6];
  const float* wo  = (const float*)d_in[7];
  const float* n1w = (const float*)d_in[8];
  const float* n1b = (const float*)d_in[9];
  const float* n2w = (const float*)d_in[10];
  const float* n2b = (const float*)d_in[11];
  const float* m1w = (const float*)d_in[12];
  const float* m1b = (const float*)d_in[13];
  const float* m2w = (const float*)d_in[14];
  const float* m2b = (const float*)d_in[15];
  const float* onw = (const float*)d_in[16];
  const float* onb = (const float*)d_in[17];

  const size_t SP = (size_t)12 * Tt * 64;
  float* x = (float*)d_ws;
  unsigned short* hP = (unsigned short*)(x + (size_t)Tt * Dm);
  unsigned short* ho = hP + SP;
  float* rt = (float*)(ho + SP);
  unsigned short* tokb = (unsigned short*)(rt + 1024*64);
  const size_t ws_need = (size_t)Tt*Dm*4 + SP*2*2 + 1024*64*4 + (size_t)12*Vp*64*2;
  const bool pre = (ws_size >= ws_need);

  float* out = (float*)d_out;
  unsigned short* gP  = (unsigned short*)d_out;
  unsigned short* qkv = (unsigned short*)((char*)d_out + (size_t)28*1024*1024);
  unsigned short* obP = (unsigned short*)((char*)d_out + (size_t)50*1024*1024);
  unsigned short* wbase = (unsigned short*)((char*)d_out + (size_t)60*1024*1024);
  const size_t SQKV = (size_t)Ll * Dm * QS;
  const size_t SWO  = (size_t)Ll * Dm * Dm;
  const size_t SM   = (size_t)Ll * Dm * Ff;
  unsigned short* qkvW = wbase;
  unsigned short* woW  = qkvW + SQKV;
  unsigned short* m1W  = woW  + SWO;
  unsigned short* m2W  = m1W  + SM;

  convwt_kernel<<<dim3(12*12, Ll), 256, 0, stream>>>(wq, qkvW, Dm, Dm, QS, 0);
  convwt_kernel<<<dim3(12*12, Ll), 256, 0, stream>>>(wk, qkvW, Dm, Dm, QS, Dm);
  convwt_kernel<<<dim3(12*12, Ll), 256, 0, stream>>>(wv, qkvW, Dm, Dm, QS, 2*Dm);
  convwt_kernel<<<dim3(12*12, Ll), 256, 0, stream>>>(wo, woW, Dm, Dm, Dm, 0);
  convwt_kernel<<<dim3(12*48, Ll), 256, 0, stream>>>(m1w, m1W, Dm, Ff, Ff, 0);
  convwt_kernel<<<dim3(48*12, Ll), 256, 0, stream>>>(m2w, m2W, Ff, Dm, Dm, 0);
  rtab_kernel<<<256, 256, 0, stream>>>(rt);
  if (pre) convtok_kernel<<<2048, 256, 0, stream>>>(tok, tokb);

  ln_kernel<0><<<Tt, 256, 0, stream>>>(tok, ids, ew, eb, x);

  for (int l = 0; l < Ll; ++l) {
    ln_kernel<1><<<Tt, 256, 0, stream>>>(x, nullptr, n1w + l*Dm, n1b + l*Dm, hP);
    gemm_big<false,false,2><<<dim3(QS/128, Tt/256), 512, 0, stream>>>(
        hP, qkvW + (size_t)l*Dm*QS, nullptr, qkv, Tt, QS, Dm);
    ttt_scan_kernel<<<192, 256, 0, stream>>>(qkv, rt, obP);
    gemm_kernel<64,64,2,false,false,true,0><<<dim3(Dm/64, Tt/64), 256, 0, stream>>>(
        obP, woW + (size_t)l*Dm*Dm, nullptr, x, x, Tt, Dm, Dm);
    ln_kernel<1><<<Tt, 256, 0, stream>>>(x, nullptr, n2w + l*Dm, n2b + l*Dm, hP);
    gemm_big<true,true,1><<<dim3(Ff/128, Tt/256), 512, 0, stream>>>(
        hP, m1W + (size_t)l*Dm*Ff, m1b + (size_t)l*Ff, gP, Tt, Ff, Dm);
    gemm_kernel<64,64,2,true,false,true,0><<<dim3(Dm/64, Tt/64), 256, 0, stream>>>(
        gP, m2W + (size_t)l*Ff*Dm, m2b + (size_t)l*Dm, x, x, Tt, Dm, Ff);
  }

  ln_kernel<1><<<Tt, 256, 0, stream>>>(x, nullptr, onw, onb, ho);
  if (pre)
    logits_kernel<true><<<dim3(6288, 1), 512, 0, stream>>>(ho, tok, tokb, out);
  else
    logits_kernel<false><<<dim3(6288, 1), 512, 0, stream>>>(ho, tok, nullptr, out);
}

// Round 21
// 3630.068 us; speedup vs baseline: 1.0380x; 1.0380x over previous
//
#include <hip/hip_runtime.h>
#include <cstdint>
#include <cstddef>

#define Dm 768
#define Hh 12
#define DHd 64
#define Ll 12
#define Vv 50257
#define Vp 50304          // padded vocab (393*128)
#define Tt 4096
#define Ff 3072
#define QS 2304           // fused qkv row stride
#define ETA (1.0f/16.0f)

typedef __attribute__((ext_vector_type(8))) _Float16 half8;
typedef __attribute__((ext_vector_type(8))) unsigned short ushort8;
typedef __attribute__((ext_vector_type(4))) float f32x4;

static __device__ __forceinline__ unsigned short f2h(float f){
  union { _Float16 h; unsigned short u; } c; c.h = (_Float16)f; return c.u;
}
static __device__ __forceinline__ float h2f(unsigned short u){
  union { unsigned short u; _Float16 h; } c; c.u = u; return (float)c.h;
}
static __device__ __forceinline__ float4 h4(ushort4 u){
  float4 f; f.x=h2f(u.x); f.y=h2f(u.y); f.z=h2f(u.z); f.w=h2f(u.w); return f;
}
// async global->LDS, 16B per lane; dest = wave-uniform base + lane*16
static __device__ __forceinline__ void gload16(const void* g, void* l){
  __builtin_amdgcn_global_load_lds((const __attribute__((address_space(1))) unsigned int*)g,
                                   (__attribute__((address_space(3))) unsigned int*)l, 16, 0, 0);
}
// panel byte offset for element (row, k) of plane with M rows
static __device__ __forceinline__ size_t pan_off(int ks, size_t M, int row, int k){
  return ((size_t)ks*M + row)*128 + (size_t)(((k*2) ^ ((row & 7) << 4)));
}

// ---- weight transform: f32 [L][K][Ns] -> swizzle-baked f16 panels [L][K/64][Nd][64] (+coff) ----
__global__ __launch_bounds__(256)
void convwt_kernel(const float* __restrict__ src, unsigned short* __restrict__ dst,
                   int K, int Ns, int Nd, int coff)
{
  const int l  = blockIdx.y;
  const int nb = blockIdx.x % (Ns/64);
  const int ks = blockIdx.x / (Ns/64);
  const int t  = threadIdx.x;
  __shared__ float tile[64][65];
  const float* W = src + (size_t)l*K*Ns;
  {
    const int r = t >> 2, c0 = (t & 3) * 16;
    const float* s = W + (size_t)(ks*64 + r)*Ns + nb*64 + c0;
    #pragma unroll
    for (int i = 0; i < 4; ++i) {
      const float4 f = *(const float4*)(s + i*4);
      tile[r][c0+i*4+0]=f.x; tile[r][c0+i*4+1]=f.y; tile[r][c0+i*4+2]=f.z; tile[r][c0+i*4+3]=f.w;
    }
  }
  __syncthreads();
  const int n   = t >> 2;
  const int kk0 = (t & 3) * 16;
  const int gn  = coff + nb*64 + n;
  unsigned short bh[16];
  #pragma unroll
  for (int i = 0; i < 16; ++i) bh[i] = f2h(tile[kk0 + i][n]);
  const size_t rowb = ((size_t)l*K*Nd + ((size_t)ks*Nd + gn)*64) * 2;
  const int swz = (gn & 7) << 4;
  char* bD = (char*)dst + rowb;
  *(ushort8*)(bD + ((kk0*2)      ^ swz)) = *(ushort8*)&bh[0];
  *(ushort8*)(bD + ((kk0*2 + 16) ^ swz)) = *(ushort8*)&bh[8];
}

// ---- tok f32 -> swizzle-baked f16 panels [12][Vp][64] ----
__global__ __launch_bounds__(256)
void convtok_kernel(const float* __restrict__ src, unsigned short* __restrict__ dst)
{
  const int total = 12 * Vp * 8;
  for (int gi = blockIdx.x*256 + threadIdx.x; gi < total; gi += gridDim.x*256) {
    const int j  = gi & 7;
    const int v  = (gi >> 3) % Vp;
    const int ks = gi / (8 * Vp);
    ushort8 u;
    if (v < Vv) {
      const float* s = src + (size_t)v*Dm + ks*64 + j*8;
      const float4 f0 = *(const float4*)s, f1 = *(const float4*)(s+4);
      u[0]=f2h(f0.x); u[1]=f2h(f0.y); u[2]=f2h(f0.z); u[3]=f2h(f0.w);
      u[4]=f2h(f1.x); u[5]=f2h(f1.y); u[6]=f2h(f1.z); u[7]=f2h(f1.w);
    } else {
      #pragma unroll
      for (int q = 0; q < 8; ++q) u[q] = 0;
    }
    const size_t rowb = ((size_t)ks*Vp + v) * 128;
    *(ushort8*)((char*)dst + rowb + ((j*16) ^ ((v&7)<<4))) = u;
  }
}

// ---- RoPE cos/sin table ----
__global__ __launch_bounds__(256)
void rtab_kernel(float* __restrict__ rt)
{
  const int idx = blockIdx.x*256 + threadIdx.x;
  if (idx >= 1024*64) return;
  const int s = idx >> 6, c = idx & 63, d = c & 31;
  const float freq = powf(10000.0f, -(float)d * (1.0f/32.0f));
  const float ang  = (float)s * freq;
  rt[idx] = (c < 32) ? cosf(ang) : sinf(ang);
}

// ---------------- LayerNorm; OMODE: 0=f32 rows, 1=f16 panels ----------------
template<int OMODE>
__global__ __launch_bounds__(256)
void ln_kernel(const float* __restrict__ in, const int* __restrict__ ids,
               const float* __restrict__ w, const float* __restrict__ b,
               void* __restrict__ o1)
{
  const int row = blockIdx.x;
  const int t = threadIdx.x;
  const float* px = in + (ids ? (size_t)ids[row] * Dm : (size_t)row * Dm);
  float x0 = px[t], x1 = px[t+256], x2 = px[t+512];
  float s  = x0 + x1 + x2;
  float s2 = x0*x0 + x1*x1 + x2*x2;
  #pragma unroll
  for (int o = 32; o > 0; o >>= 1) { s += __shfl_xor(s, o); s2 += __shfl_xor(s2, o); }
  __shared__ float ls[4], ls2[4];
  if ((t & 63) == 0) { ls[t>>6] = s; ls2[t>>6] = s2; }
  __syncthreads();
  s  = ls[0]+ls[1]+ls[2]+ls[3];
  s2 = ls2[0]+ls2[1]+ls2[2]+ls2[3];
  const float mu  = s * (1.0f/Dm);
  const float var = s2 * (1.0f/Dm) - mu*mu;
  const float rs  = rsqrtf(var + 1e-5f);
  #pragma unroll
  for (int i = 0; i < 3; ++i) {
    const int c = t + i*256;
    const float xv = (i==0) ? x0 : (i==1) ? x1 : x2;
    const float vv_ = (xv-mu)*rs*w[c] + b[c];
    if (OMODE == 0) {
      ((float*)o1)[(size_t)row * Dm + c] = vv_;
    } else {
      *(unsigned short*)((char*)o1 + pan_off(c >> 6, Tt, row, c & 63)) = f2h(vv_);
    }
  }
}

// ---------------- TTT scan, fused RoPE, dbuf k/q LDS, 2 barriers/chunk, v prefetched ----------------
static __device__ __forceinline__ float4 rot4(float4 a, float4 p, float4 rc, float4 rs, bool hi){
  float4 o;
  if (hi) { o.x = p.x*rs.x + a.x*rc.x; o.y = p.y*rs.y + a.y*rc.y;
            o.z = p.z*rs.z + a.z*rc.z; o.w = p.w*rs.w + a.w*rc.w; }
  else    { o.x = a.x*rc.x - p.x*rs.x; o.y = a.y*rc.y - p.y*rs.y;
            o.z = a.z*rc.z - p.z*rs.z; o.w = a.w*rc.w - p.w*rs.w; }
  return o;
}

__global__ __launch_bounds__(256)
void ttt_scan_kernel(const unsigned short* __restrict__ qkv, const float* __restrict__ rt,
                     unsigned short* __restrict__ ob)
{
  const int head = blockIdx.x >> 2;
  const int es   = blockIdx.x & 3;
  const int b  = head / Hh;
  const int hd = head % Hh;
  const int t  = threadIdx.x;
  __shared__ float Wm[16][68];
  __shared__ float kms[2][16][68];
  __shared__ float qms[2][16][68];
  __shared__ float EsT[16][20];
  __shared__ float Asc[16][20];

  const int e   = t & 15;
  const int m16 = t >> 4;
  const int sr  = t >> 4;
  const int sc  = (t & 15) * 4;
  const bool hi = (sc >= 32);

  for (int i = t; i < 16*68; i += 256) ((float*)Wm)[i] = 0.0f;

  const int tb0 = b * 1024;
  const size_t gbase = (size_t)hd * DHd;

  {
    const size_t ro = (size_t)(tb0 + sr)*QS + gbase;
    const float4 kr = h4(*(const ushort4*)&qkv[ro + Dm + sc]);
    const float4 kp = h4(*(const ushort4*)&qkv[ro + Dm + (sc^32)]);
    const float4 qr = h4(*(const ushort4*)&qkv[ro + sc]);
    const float4 qp = h4(*(const ushort4*)&qkv[ro + (sc^32)]);
    const float4 rc = *(const float4*)&rt[sr*64 + (sc&31)];
    const float4 rs = *(const float4*)&rt[sr*64 + 32 + (sc&31)];
    *(float4*)&kms[0][sr][sc] = rot4(kr, kp, rc, rs, hi);
    *(float4*)&qms[0][sr][sc] = rot4(qr, qp, rc, rs, hi);
  }
  float4 krR, qrR;
  {
    const size_t ro = (size_t)(tb0 + 16 + sr)*QS + gbase;
    const float4 kr = h4(*(const ushort4*)&qkv[ro + Dm + sc]);
    const float4 kp = h4(*(const ushort4*)&qkv[ro + Dm + (sc^32)]);
    const float4 qr = h4(*(const ushort4*)&qkv[ro + sc]);
    const float4 qp = h4(*(const ushort4*)&qkv[ro + (sc^32)]);
    const float4 rc = *(const float4*)&rt[(16+sr)*64 + (sc&31)];
    const float4 rs = *(const float4*)&rt[(16+sr)*64 + 32 + (sc&31)];
    krR = rot4(kr, kp, rc, rs, hi);
    qrR = rot4(qr, qp, rc, rs, hi);
  }
  float vreg = h2f(qkv[(size_t)(tb0 + m16)*QS + 2*Dm + gbase + es*16 + e]);
  __syncthreads();

  for (int c = 0; c < 64; ++c) {
    const int buf = c & 1;
    const int tb = tb0 + c*16;
    float aE = -vreg, aO = 0.0f, aA = 0.0f;
    #pragma unroll
    for (int d4 = 0; d4 < 64; d4 += 4) {
      const float4 wv = *(const float4*)&Wm[e][d4];
      const float4 km = *(const float4*)&kms[buf][m16][d4];
      const float4 qm = *(const float4*)&qms[buf][m16][d4];
      const float4 ke = *(const float4*)&kms[buf][e][d4];
      aE += km.x*wv.x + km.y*wv.y + km.z*wv.z + km.w*wv.w;
      aO += qm.x*wv.x + qm.y*wv.y + qm.z*wv.z + qm.w*wv.w;
      aA += qm.x*ke.x + qm.y*ke.y + qm.z*ke.z + qm.w*ke.w;
    }
    EsT[e][m16] = aE;
    Asc[m16][e] = (e <= m16) ? (-ETA * aA) : 0.0f;
    if (c < 63) vreg = h2f(qkv[(size_t)(tb + 16 + m16)*QS + 2*Dm + gbase + es*16 + e]);
    __syncthreads();
    float esr[16];
    float acc = aO;
    #pragma unroll
    for (int n4 = 0; n4 < 16; n4 += 4) {
      const float4 ev = *(const float4*)&EsT[e][n4];
      const float4 av = *(const float4*)&Asc[m16][n4];
      esr[n4]=ev.x; esr[n4+1]=ev.y; esr[n4+2]=ev.z; esr[n4+3]=ev.w;
      acc += av.x*ev.x + av.y*ev.y + av.z*ev.z + av.w*ev.w;
    }
    *(unsigned short*)((char*)ob + pan_off(hd, Tt, tb + m16, es*16 + e)) = f2h(acc);
    {
      const int d0 = m16 * 4;
      float4 wacc; wacc.x = 0.0f; wacc.y = 0.0f; wacc.z = 0.0f; wacc.w = 0.0f;
      #pragma unroll
      for (int m = 0; m < 16; ++m) {
        const float4 km = *(const float4*)&kms[buf][m][d0];
        const float ev = esr[m];
        wacc.x += km.x*ev; wacc.y += km.y*ev; wacc.z += km.z*ev; wacc.w += km.w*ev;
      }
      float4 wv = *(float4*)&Wm[e][d0];
      wv.x -= ETA*wacc.x; wv.y -= ETA*wacc.y; wv.z -= ETA*wacc.z; wv.w -= ETA*wacc.w;
      *(float4*)&Wm[e][d0] = wv;
    }
    if (c < 63) {
      *(float4*)&kms[buf^1][sr][sc] = krR;
      *(float4*)&qms[buf^1][sr][sc] = qrR;
    }
    if (c < 62) {
      const size_t ro = (size_t)(tb + 32 + sr)*QS + gbase;
      const float4 kr = h4(*(const ushort4*)&qkv[ro + Dm + sc]);
      const float4 kp = h4(*(const ushort4*)&qkv[ro + Dm + (sc^32)]);
      const float4 qr = h4(*(const ushort4*)&qkv[ro + sc]);
      const float4 qp = h4(*(const ushort4*)&qkv[ro + (sc^32)]);
      const int sN = (c+2)*16 + sr;
      const float4 rc = *(const float4*)&rt[sN*64 + (sc&31)];
      const float4 rs = *(const float4*)&rt[sN*64 + 32 + (sc&31)];
      krR = rot4(kr, kp, rc, rs, hi);
      qrR = rot4(qr, qp, rc, rs, hi);
    }
    __syncthreads();
  }
}

static __device__ __forceinline__ float gelu_f(float x){
  const float u = 0.7978845608028654f * (x + 0.044715f * x*x*x);
  return 0.5f * x * (1.0f + tanhf(u));
}

// ---------------- f16 MFMA GEMM (256-thr, single-buffer, gload_lds panels, KP k-panels/stage) ----------------
// OUT: 0=f32 rows (+RES), 1=f16 panel plane, 2=f16 rows
template<int TM, int TN, int KP, bool BIAS, bool GELU_, bool RES, int OUT>
__global__ __launch_bounds__(256)
void gemm_kernel(const unsigned short* __restrict__ A, const unsigned short* __restrict__ B,
                 const float* __restrict__ bias, const float* __restrict__ res,
                 void* __restrict__ o1, int M, int N, int K)
{
  constexpr int FM = TM / 32;
  constexpr int FN = TN / 32;
  __shared__ __attribute__((aligned(16))) unsigned short As[KP*TM*64];
  __shared__ __attribute__((aligned(16))) unsigned short Bs[KP*TN*64];
  const int t    = threadIdx.x;
  const int lane = t & 63;
  const int fr   = lane & 15;
  const int fg   = lane >> 4;
  const int wave = t >> 6;
  const int wm   = (wave >> 1) * (TM/2);
  const int wn   = (wave & 1) * (TN/2);
  const int row0 = blockIdx.y * TM;
  const int n0   = blockIdx.x * TN;

  f32x4 acc[FM][FN];
  #pragma unroll
  for (int i = 0; i < FM; ++i)
    #pragma unroll
    for (int j = 0; j < FN; ++j)
      #pragma unroll
      for (int r = 0; r < 4; ++r) acc[i][j][r] = 0.0f;

  const int NI = K / (64*KP);
  for (int it = 0; it < NI; ++it) {
    #pragma unroll
    for (int p = 0; p < KP; ++p) {
      const int ks = it*KP + p;
      {
        const char* gB = (const char*)B + ((size_t)ks*N + n0) * 128;
        char* lB = (char*)Bs + p*(TN*128);
        #pragma unroll
        for (int r = 0; r < TN/32; ++r) {
          const int chunk = (r*4 + wave) * 1024;
          gload16(gB + chunk + lane*16, lB + chunk);
        }
      }
      {
        const char* gA = (const char*)A + ((size_t)ks*M + row0) * 128;
        char* lA = (char*)As + p*(TM*128);
        #pragma unroll
        for (int r = 0; r < TM/32; ++r) {
          const int chunk = (r*4 + wave) * 1024;
          gload16(gA + chunk + lane*16, lA + chunk);
        }
      }
    }
    __syncthreads();
    #pragma unroll
    for (int p = 0; p < KP; ++p) {
      #pragma unroll
      for (int kh = 0; kh < 2; ++kh) {
        half8 af[FM], bf[FN];
        const int swz = (fr & 7) << 4;
        #pragma unroll
        for (int mt = 0; mt < FM; ++mt)
          af[mt] = *(const half8*)((const char*)As + p*(TM*128) + (((wm + mt*16 + fr)*128 + kh*64 + fg*16) ^ swz));
        #pragma unroll
        for (int nt = 0; nt < FN; ++nt)
          bf[nt] = *(const half8*)((const char*)Bs + p*(TN*128) + (((wn + nt*16 + fr)*128 + kh*64 + fg*16) ^ swz));
        #pragma unroll
        for (int mt = 0; mt < FM; ++mt)
          #pragma unroll
          for (int nt = 0; nt < FN; ++nt)
            acc[mt][nt] = __builtin_amdgcn_mfma_f32_16x16x32_f16(af[mt], bf[nt], acc[mt][nt], 0, 0, 0);
      }
    }
    __syncthreads();
  }

  #pragma unroll
  for (int mt = 0; mt < FM; ++mt) {
    #pragma unroll
    for (int nt = 0; nt < FN; ++nt) {
      const int col = n0 + wn + nt*16 + fr;
      const int rbase = row0 + wm + mt*16 + fg*4;
      const float bcol = BIAS ? bias[col] : 0.0f;
      #pragma unroll
      for (int r = 0; r < 4; ++r) {
        float val = acc[mt][nt][r];
        if (BIAS)  val += bcol;
        if (GELU_) val = gelu_f(val);
        if (OUT == 1) {
          *(unsigned short*)((char*)o1 + pan_off(col >> 6, M, rbase + r, col & 63)) = f2h(val);
        } else if (OUT == 2) {
          ((unsigned short*)o1)[(size_t)(rbase + r) * N + col] = f2h(val);
        } else {
          const size_t off = (size_t)(rbase + r) * N + col;
          float v2 = val;
          if (RES) v2 += res[off];
          ((float*)o1)[off] = v2;
        }
      }
    }
  }
}

// ---------------- wide f16 GEMM: 128x128 tile, 512 thr (8 waves 2m x 4n, wave tile 64x32) ----------------
// OUT: 1=f16 panel plane, 2=f16 rows
template<bool BIAS, bool GELU_, int OUT>
__global__ __launch_bounds__(512)
void gemm_wide(const unsigned short* __restrict__ A, const unsigned short* __restrict__ B,
               const float* __restrict__ bias, void* __restrict__ o1, int M, int N, int K)
{
  __shared__ __attribute__((aligned(16))) unsigned short As[128*64];  // 16 KB
  __shared__ __attribute__((aligned(16))) unsigned short Bs[128*64];  // 16 KB
  const int t    = threadIdx.x;
  const int lane = t & 63;
  const int fr   = lane & 15;
  const int fg   = lane >> 4;
  const int w    = t >> 6;                   // 0..7
  const int wm   = (w >> 2) * 64;            // 2 m-waves
  const int wn   = (w & 3) * 32;             // 4 n-waves
  const int row0 = blockIdx.y * 128;
  const int n0   = blockIdx.x * 128;

  f32x4 acc[4][2];
  #pragma unroll
  for (int i = 0; i < 4; ++i)
    #pragma unroll
    for (int j = 0; j < 2; ++j)
      #pragma unroll
      for (int r = 0; r < 4; ++r) acc[i][j][r] = 0.0f;

  const int NK = K >> 6;
  for (int ks = 0; ks < NK; ++ks) {
    { // A: 16 KB = 16 chunks; 8 waves x 2
      const char* gA = (const char*)A + ((size_t)ks*M + row0) * 128;
      #pragma unroll
      for (int r = 0; r < 2; ++r) {
        const int chunk = (r*8 + w) * 1024;
        gload16(gA + chunk + lane*16, (char*)As + chunk);
      }
    }
    { // B: 16 KB = 16 chunks; 8 waves x 2
      const char* gB = (const char*)B + ((size_t)ks*N + n0) * 128;
      #pragma unroll
      for (int r = 0; r < 2; ++r) {
        const int chunk = (r*8 + w) * 1024;
        gload16(gB + chunk + lane*16, (char*)Bs + chunk);
      }
    }
    __syncthreads();
    #pragma unroll
    for (int kh = 0; kh < 2; ++kh) {
      half8 af[4], bf[2];
      const int swz = (fr & 7) << 4;
      #pragma unroll
      for (int mt = 0; mt < 4; ++mt)
        af[mt] = *(const half8*)((const char*)As + (((wm + mt*16 + fr)*128 + kh*64 + fg*16) ^ swz));
      #pragma unroll
      for (int nt = 0; nt < 2; ++nt)
        bf[nt] = *(const half8*)((const char*)Bs + (((wn + nt*16 + fr)*128 + kh*64 + fg*16) ^ swz));
      #pragma unroll
      for (int mt = 0; mt < 4; ++mt)
        #pragma unroll
        for (int nt = 0; nt < 2; ++nt)
          acc[mt][nt] = __builtin_amdgcn_mfma_f32_16x16x32_f16(af[mt], bf[nt], acc[mt][nt], 0, 0, 0);
    }
    __syncthreads();
  }

  #pragma unroll
  for (int mt = 0; mt < 4; ++mt) {
    #pragma unroll
    for (int nt = 0; nt < 2; ++nt) {
      const int col = n0 + wn + nt*16 + fr;
      const int rbase = row0 + wm + mt*16 + fg*4;
      const float bcol = BIAS ? bias[col] : 0.0f;
      #pragma unroll
      for (int r = 0; r < 4; ++r) {
        float val = acc[mt][nt][r];
        if (BIAS)  val += bcol;
        if (GELU_) val = gelu_f(val);
        if (OUT == 1) {
          *(unsigned short*)((char*)o1 + pan_off(col >> 6, M, rbase + r, col & 63)) = f2h(val);
        } else {
          ((unsigned short*)o1)[(size_t)(rbase + r) * N + col] = f2h(val);
        }
      }
    }
  }
}

// ---------------- logits GEMM: 256x128 block tile, 512 thr ----------------
template<bool PRE>
__global__ __launch_bounds__(512)
void logits_kernel(const unsigned short* __restrict__ hop, const float* __restrict__ tok,
                   const unsigned short* __restrict__ tokb, float* __restrict__ C)
{
  __shared__ __attribute__((aligned(16))) unsigned short As[256*64];
  __shared__ __attribute__((aligned(16))) unsigned short Bs[128*64];
  int bid = blockIdx.x;
  bid = (bid & 7) * 786 + (bid >> 3);
  const int n0   = (bid >> 4) * 128;
  const int row0 = (bid & 15) * 256;

  const int t    = threadIdx.x;
  const int lane = t & 63;
  const int fr   = lane & 15;
  const int fg   = lane >> 4;
  const int w    = t >> 6;
  const int wm   = (w >> 1) * 64;
  const int wn   = (w & 1) * 64;
  const int arow = t >> 2;
  const int ach  = (t & 3) * 16;

  f32x4 acc[4][4];
  #pragma unroll
  for (int i = 0; i < 4; ++i)
    #pragma unroll
    for (int j = 0; j < 4; ++j)
      #pragma unroll
      for (int r = 0; r < 4; ++r) acc[i][j][r] = 0.0f;

  for (int ks = 0; ks < 12; ++ks) {
    {
      const char* gA = (const char*)hop + ((size_t)ks*Tt + row0) * 128;
      #pragma unroll
      for (int r = 0; r < 4; ++r) {
        const int chunk = (r*8 + w) * 1024;
        gload16(gA + chunk + lane*16, (char*)As + chunk);
      }
    }
    if (PRE) {
      const char* gB = (const char*)tokb + ((size_t)ks*Vp + n0) * 128;
      #pragma unroll
      for (int r = 0; r < 2; ++r) {
        const int chunk = (r*8 + w) * 1024;
        gload16(gB + chunk + lane*16, (char*)Bs + chunk);
      }
    } else {
      const int brow = n0 + arow;
      ushort8 u;
      if (brow < Vv) {
        const float* src = &tok[(size_t)brow * Dm + ks*64 + ach];
        const float4 f0 = *(const float4*)src;
        const float4 f1 = *(const float4*)(src + 4);
        const float4 f2 = *(const float4*)(src + 8);
        const float4 f3 = *(const float4*)(src + 12);
        u[0]=f2h(f0.x); u[1]=f2h(f0.y); u[2]=f2h(f0.z); u[3]=f2h(f0.w);
        u[4]=f2h(f1.x); u[5]=f2h(f1.y); u[6]=f2h(f1.z); u[7]=f2h(f1.w);
        const int byt0 = (arow*128 + ach*2) ^ ((arow & 7) << 4);
        *(ushort8*)((char*)Bs + byt0) = u;
        u[0]=f2h(f2.x); u[1]=f2h(f2.y); u[2]=f2h(f2.z); u[3]=f2h(f2.w);
        u[4]=f2h(f3.x); u[5]=f2h(f3.y); u[6]=f2h(f3.z); u[7]=f2h(f3.w);
        const int byt1 = (arow*128 + ach*2 + 16) ^ ((arow & 7) << 4);
        *(ushort8*)((char*)Bs + byt1) = u;
      } else {
        #pragma unroll
        for (int q = 0; q < 8; ++q) u[q] = 0;
        const int byt0 = (arow*128 + ach*2) ^ ((arow & 7) << 4);
        const int byt1 = (arow*128 + ach*2 + 16) ^ ((arow & 7) << 4);
        *(ushort8*)((char*)Bs + byt0) = u;
        *(ushort8*)((char*)Bs + byt1) = u;
      }
    }
    __syncthreads();
    #pragma unroll
    for (int kh = 0; kh < 2; ++kh) {
      half8 af[4], bf[4];
      const int swz = (fr & 7) << 4;
      #pragma unroll
      for (int mt = 0; mt < 4; ++mt)
        af[mt] = *(const half8*)((const char*)As + (((wm + mt*16 + fr)*128 + kh*64 + fg*16) ^ swz));
      #pragma unroll
      for (int nt = 0; nt < 4; ++nt)
        bf[nt] = *(const half8*)((const char*)Bs + (((wn + nt*16 + fr)*128 + kh*64 + fg*16) ^ swz));
      #pragma unroll
      for (int mt = 0; mt < 4; ++mt)
        #pragma unroll
        for (int nt = 0; nt < 4; ++nt)
          acc[mt][nt] = __builtin_amdgcn_mfma_f32_16x16x32_f16(af[mt], bf[nt], acc[mt][nt], 0, 0, 0);
    }
    __syncthreads();
  }

  #pragma unroll
  for (int mt = 0; mt < 4; ++mt) {
    #pragma unroll
    for (int nt = 0; nt < 4; ++nt) {
      const int col = n0 + wn + nt*16 + fr;
      if (col < Vv) {
        const int rbase = row0 + wm + mt*16 + fg*4;
        #pragma unroll
        for (int r = 0; r < 4; ++r)
          C[(size_t)(rbase + r) * Vv + col] = acc[mt][nt][r];
      }
    }
  }
}

// ---------------- host-side orchestration ----------------
extern "C" void kernel_launch(void* const* d_in, const int* in_sizes, int n_in,
                              void* d_out, int out_size, void* d_ws, size_t ws_size,
                              hipStream_t stream)
{
  const int*   ids = (const int*)  d_in[0];
  const float* tok = (const float*)d_in[1];
  const float* ew  = (const float*)d_in[2];
  const float* eb  = (const float*)d_in[3];
  const float* wq  = (const float*)d_in[4];
  const float* wk  = (const float*)d_in[5];
  const float* wv  = (const float*)d_in[6];
  const float* wo  = (const float*)d_in[7];
  const float* n1w = (const float*)d_in[8];
  const float* n1b = (const float*)d_in[9];
  const float* n2w = (const float*)d_in[10];
  const float* n2b = (const float*)d_in[11];
  const float* m1w = (const float*)d_in[12];
  const float* m1b = (const float*)d_in[13];
  const float* m2w = (const float*)d_in[14];
  const float* m2b = (const float*)d_in[15];
  const float* onw = (const float*)d_in[16];
  const float* onb = (const float*)d_in[17];

  const size_t SP = (size_t)12 * Tt * 64;
  float* x = (float*)d_ws;
  unsigned short* hP = (unsigned short*)(x + (size_t)Tt * Dm);
  unsigned short* ho = hP + SP;
  float* rt = (float*)(ho + SP);
  unsigned short* tokb = (unsigned short*)(rt + 1024*64);
  const size_t ws_need = (size_t)Tt*Dm*4 + SP*2*2 + 1024*64*4 + (size_t)12*Vp*64*2;
  const bool pre = (ws_size >= ws_need);

  float* out = (float*)d_out;
  unsigned short* gP  = (unsigned short*)d_out;
  unsigned short* qkv = (unsigned short*)((char*)d_out + (size_t)28*1024*1024);
  unsigned short* obP = (unsigned short*)((char*)d_out + (size_t)50*1024*1024);
  unsigned short* wbase = (unsigned short*)((char*)d_out + (size_t)60*1024*1024);
  const size_t SQKV = (size_t)Ll * Dm * QS;
  const size_t SWO  = (size_t)Ll * Dm * Dm;
  const size_t SM   = (size_t)Ll * Dm * Ff;
  unsigned short* qkvW = wbase;
  unsigned short* woW  = qkvW + SQKV;
  unsigned short* m1W  = woW  + SWO;
  unsigned short* m2W  = m1W  + SM;

  convwt_kernel<<<dim3(12*12, Ll), 256, 0, stream>>>(wq, qkvW, Dm, Dm, QS, 0);
  convwt_kernel<<<dim3(12*12, Ll), 256, 0, stream>>>(wk, qkvW, Dm, Dm, QS, Dm);
  convwt_kernel<<<dim3(12*12, Ll), 256, 0, stream>>>(wv, qkvW, Dm, Dm, QS, 2*Dm);
  convwt_kernel<<<dim3(12*12, Ll), 256, 0, stream>>>(wo, woW, Dm, Dm, Dm, 0);
  convwt_kernel<<<dim3(12*48, Ll), 256, 0, stream>>>(m1w, m1W, Dm, Ff, Ff, 0);
  convwt_kernel<<<dim3(48*12, Ll), 256, 0, stream>>>(m2w, m2W, Ff, Dm, Dm, 0);
  rtab_kernel<<<256, 256, 0, stream>>>(rt);
  if (pre) convtok_kernel<<<2048, 256, 0, stream>>>(tok, tokb);

  ln_kernel<0><<<Tt, 256, 0, stream>>>(tok, ids, ew, eb, x);

  for (int l = 0; l < Ll; ++l) {
    ln_kernel<1><<<Tt, 256, 0, stream>>>(x, nullptr, n1w + l*Dm, n1b + l*Dm, hP);
    gemm_wide<false,false,2><<<dim3(QS/128, Tt/128), 512, 0, stream>>>(
        hP, qkvW + (size_t)l*Dm*QS, nullptr, qkv, Tt, QS, Dm);
    ttt_scan_kernel<<<192, 256, 0, stream>>>(qkv, rt, obP);
    gemm_kernel<64,64,2,false,false,true,0><<<dim3(Dm/64, Tt/64), 256, 0, stream>>>(
        obP, woW + (size_t)l*Dm*Dm, nullptr, x, x, Tt, Dm, Dm);
    ln_kernel<1><<<Tt, 256, 0, stream>>>(x, nullptr, n2w + l*Dm, n2b + l*Dm, hP);
    gemm_wide<true,true,1><<<dim3(Ff/128, Tt/128), 512, 0, stream>>>(
        hP, m1W + (size_t)l*Dm*Ff, m1b + (size_t)l*Ff, gP, Tt, Ff, Dm);
    gemm_kernel<64,64,2,true,false,true,0><<<dim3(Dm/64, Tt/64), 256, 0, stream>>>(
        gP, m2W + (size_t)l*Ff*Dm, m2b + (size_t)l*Dm, x, x, Tt, Dm, Ff);
  }

  ln_kernel<1><<<Tt, 256, 0, stream>>>(x, nullptr, onw, onb, ho);
  if (pre)
    logits_kernel<true><<<dim3(6288, 1), 512, 0, stream>>>(ho, tok, tokb, out);
  else
    logits_kernel<false><<<dim3(6288, 1), 512, 0, stream>>>(ho, tok, nullptr, out);
}